// Round 16
// baseline (471.498 us; speedup 1.0000x reference)
//
#include <hip/hip_runtime.h>

typedef unsigned short u16;
typedef unsigned int   u32;
typedef __attribute__((ext_vector_type(8))) short short8;
typedef __attribute__((ext_vector_type(4))) short short4v;
typedef __attribute__((ext_vector_type(4))) float f32x4;

__device__ __forceinline__ float bf2f(u16 h){
    return __uint_as_float(((u32)h) << 16);
}
__device__ __forceinline__ u16 f2bf(float f){
    u32 u = __float_as_uint(f);
    u += 0x7fffu + ((u >> 16) & 1u);   // RNE
    return (u16)(u >> 16);
}

// ---- one-block probe: dtype flags + small tensors + ticket init -----------
__global__ void probe_all(const u16* __restrict__ w1, const int* __restrict__ ei,
                          const void* b1, const void* b2, const void* b3,
                          const void* b4, const void* av,
                          int* __restrict__ f32f, int* __restrict__ efmt,
                          int* __restrict__ zf, int* __restrict__ tk1,
                          int* __restrict__ tk2,
                          u16* d1, u16* d2, u16* d3, u16* d4, u16* da){
    __shared__ int sf32, sfmt;
    int t = threadIdx.x;                 // 256
    if (t == 0){ sf32 = 0; sfmt = 0; }
    __syncthreads();
    {   // fp32-vs-bf16 probe on W1 (~N(0,0.02)): bf16 never has |v|>=1
        int huge = 0;
        #pragma unroll
        for (int k = 0; k < 16; k++){
            u16 h = w1[t * 16 + k];
            if (((h >> 7) & 0xFF) >= 0x7F) huge = 1;
        }
        if (huge) atomicOr(&sf32, 1);
    }
    if (ei[2*t + 1] != 0) atomicOr(&sfmt, 1);   // int64 => odd words zero
    __syncthreads();
    int f32 = sf32, fmt = sfmt;
    if (t == 0){ f32f[0] = f32; efmt[0] = fmt; zf[0] = 0; tk1[0] = 0; tk2[0] = 0; }
    #define CV(s,i) (f32 ? f2bf(((const float*)(s))[i]) : ((const u16*)(s))[i])
    d1[t]       = CV(b1, t);
    d1[t + 256] = CV(b1, t + 256);
    d2[t] = CV(b2, t);
    d3[t] = CV(b3, t);
    d4[t] = CV(b4, t);
    if (t == 0) da[0] = CV(av, 0);
    #undef CV
}

// (2,E) block layout per jax: src = row0, dst = row1
__device__ __forceinline__ int eload(const int* ei, int fmt, int idx){
    return fmt ? ei[idx] : ei[2*idx];    // int64 little-endian: low word
}

// ---------------- degree / CSR build (dst-keyed) ---------------------------
__global__ void deg_count(const int* __restrict__ ei, const int* __restrict__ efmt,
                          int* __restrict__ cnt, int E, int N){
    int e = blockIdx.x * 256 + threadIdx.x;
    if (e < E){
        int d = eload(ei, efmt[0], E + e);
        if ((unsigned)d < (unsigned)N) atomicAdd(&cnt[d], 1);
    }
}

__global__ void scan1(const int* __restrict__ cnt, int* __restrict__ incl,
                      int* __restrict__ bsum, int N){
    __shared__ int s[256];
    int t = threadIdx.x, i = blockIdx.x * 256 + t;
    int v = (i < N) ? cnt[i] : 0;
    s[t] = v;
    __syncthreads();
    #pragma unroll
    for (int off = 1; off < 256; off <<= 1){
        int u = (t >= off) ? s[t - off] : 0;
        __syncthreads();
        s[t] += u;
        __syncthreads();
    }
    if (i < N) incl[i] = s[t];
    if (t == 255) bsum[blockIdx.x] = s[255];
}

__global__ void scan2(const int* __restrict__ bsum, int* __restrict__ boff,
                      int nb, int* __restrict__ rowstart_last){
    __shared__ int s[128];
    int t = threadIdx.x;
    int v = (t < nb) ? bsum[t] : 0;
    s[t] = v;
    __syncthreads();
    #pragma unroll
    for (int off = 1; off < 128; off <<= 1){
        int u = (t >= off) ? s[t - off] : 0;
        __syncthreads();
        s[t] += u;
        __syncthreads();
    }
    if (t < nb) boff[t] = s[t] - v;
    if (t == nb - 1) rowstart_last[0] = s[t];
}

__global__ void scan3(const int* __restrict__ cnt, const int* __restrict__ incl,
                      const int* __restrict__ boff, int* __restrict__ rowstart,
                      int* __restrict__ cursor, float* __restrict__ dis, int N){
    int i = blockIdx.x * 256 + threadIdx.x;
    if (i < N){
        int v = cnt[i];
        int rsv = boff[blockIdx.x] + incl[i] - v;
        rowstart[i] = rsv;
        cursor[i]   = rsv;
        dis[i] = rsqrtf((float)v + 1.0f);
    }
}

__global__ void csr_fill(const int* __restrict__ ei, const int* __restrict__ efmt,
                         int* __restrict__ cursor, int* __restrict__ csr_src,
                         int E, int N){
    int e = blockIdx.x * 256 + threadIdx.x;
    if (e < E){
        int fmt = efmt[0];
        int d = eload(ei, fmt, E + e);
        if ((unsigned)d < (unsigned)N){
            int p = atomicAdd(&cursor[d], 1);
            csr_src[p] = eload(ei, fmt, e);
        }
    }
}

// -------- all 4 weights: convert+transpose in ONE launch -------------------
__global__ void transpose_all(const void* w1, const void* w2, const void* w3,
                              const void* w4, const int* __restrict__ flag,
                              u16* o1, u16* o2, u16* o3, u16* o4){
    const void* in; u16* out; int K, N;
    switch (blockIdx.z){
        case 0:  in = w1; out = o1; K = 512; N = 512; break;
        case 1:  in = w2; out = o2; K = 512; N = 256; break;
        case 2:  in = w3; out = o3; K = 256; N = 256; break;
        default: in = w4; out = o4; K = 256; N = 256; break;
    }
    int bx = blockIdx.x * 32;   // n
    int by = blockIdx.y * 32;   // k
    if (bx >= N || by >= K) return;
    __shared__ u16 t[32][33];
    int x = threadIdx.x, y = threadIdx.y;   // (32,8)
    int f32 = flag[0];
    #pragma unroll
    for (int i = 0; i < 32; i += 8){
        size_t idx = (size_t)(by + y + i) * N + bx + x;
        t[y + i][x] = f32 ? f2bf(((const float*)in)[idx]) : ((const u16*)in)[idx];
    }
    __syncthreads();
    #pragma unroll
    for (int i = 0; i < 32; i += 8)
        out[(size_t)(bx + y + i) * K + by + x] = t[x][y + i];
}

// ---------------- MFMA GEMM: C[M][N] = A[M][K] * BT[N][K]^T ----------------
// 64x128 tile, 256 thr = 4 waves (2x2), each wave 32x64 = 2x4 16x16 frags.
#define TM 64
#define TN 128
#define BK 32
#define BKP 40   // padded LDS row

template<int MODE, int OUTF>   // MODE: 0 plain,1 +bias,2 +bias+ELU; OUTF: 0 bf16,1 fp32
__global__ __launch_bounds__(256) void gemm_mfma(
    const void* __restrict__ A, const int* __restrict__ af32,
    const u16* __restrict__ BT,
    const u16* __restrict__ bias, void* __restrict__ Cv,
    int M, int K, int N)
{
    __shared__ __align__(16) u16 As[TM * BKP];
    __shared__ __align__(16) u16 Bs[TN * BKP];
    int tid  = threadIdx.x;
    int lane = tid & 63;
    int wave = tid >> 6;
    int waveM = wave >> 1, waveN = wave & 1;
    int bm = blockIdx.x * TM;
    int bn = blockIdx.y * TN;
    int f32 = af32[0];

    f32x4 acc[2][4] = {};

    int alr = tid >> 2;            // A: 0..63 row, 4 thr/row
    int alc = (tid & 3) * 8;
    int blr = tid >> 1;            // B: 0..127 row, 2 thr/row
    int blc = (tid & 1) * 16;

    for (int k0 = 0; k0 < K; k0 += BK){
        {   // A tile 64x32 (M-guarded)
            int gr = bm + alr;
            short8 v = {0,0,0,0,0,0,0,0};
            if (gr < M){
                if (f32){
                    const float* p = (const float*)A + (size_t)gr * K + k0 + alc;
                    f32x4 a0 = *(const f32x4*)p;
                    f32x4 a1 = *(const f32x4*)(p + 4);
                    #pragma unroll
                    for (int j = 0; j < 4; j++){
                        v[j]   = (short)f2bf(a0[j]);
                        v[4+j] = (short)f2bf(a1[j]);
                    }
                } else {
                    v = *(const short8*)((const u16*)A + (size_t)gr * K + k0 + alc);
                }
            }
            *(short8*)&As[alr * BKP + alc] = v;
        }
        {   // B tile 128x32 from WT[N][K]
            const u16* p = BT + (size_t)(bn + blr) * K + k0 + blc;
            short8 v0 = *(const short8*)p;
            short8 v1 = *(const short8*)(p + 8);
            *(short8*)&Bs[blr * BKP + blc]     = v0;
            *(short8*)&Bs[blr * BKP + blc + 8] = v1;
        }
        __syncthreads();
        int q = lane >> 4;
        int r16 = lane & 15;
        short8 af[2], bfr[4];
        #pragma unroll
        for (int i = 0; i < 2; i++)
            af[i]  = *(const short8*)&As[(waveM*32 + i*16 + r16) * BKP + q*8];
        #pragma unroll
        for (int j = 0; j < 4; j++)
            bfr[j] = *(const short8*)&Bs[(waveN*64 + j*16 + r16) * BKP + q*8];
        #pragma unroll
        for (int i = 0; i < 2; i++)
            #pragma unroll
            for (int j = 0; j < 4; j++)
                acc[i][j] = __builtin_amdgcn_mfma_f32_16x16x32_bf16(af[i], bfr[j], acc[i][j], 0, 0, 0);
        __syncthreads();
    }

    int q = lane >> 4;
    int c16 = lane & 15;
    #pragma unroll
    for (int i = 0; i < 2; i++){
        #pragma unroll
        for (int j = 0; j < 4; j++){
            int gcol = bn + waveN*64 + j*16 + c16;
            float bvv = (MODE >= 1) ? bf2f(bias[gcol]) : 0.f;
            #pragma unroll
            for (int r = 0; r < 4; r++){
                int grow = bm + waveM*32 + i*16 + q*4 + r;
                if (grow < M){
                    float v = acc[i][j][r] + bvv;
                    if (MODE == 2) v = (v > 0.f) ? v : expm1f(v);
                    if (OUTF) ((float*)Cv)[(size_t)grow * N + gcol] = v;
                    else      ((u16*)Cv)[(size_t)grow * N + gcol] = f2bf(v);
                }
            }
        }
    }
}

// ---------------- work-stealing aggregation (+bias+PReLU) ------------------
// One wave per node; nodes dispensed 4-at-a-time from a ticket counter.
// out = prelu( di*( sum_e dis[s_e]*row_e + di*row_self ) + bias )
template<int F> struct AggVec;
template<> struct AggVec<512>{ using T = short8;  enum{ EPL = 8 }; };
template<> struct AggVec<256>{ using T = short4v; enum{ EPL = 4 }; };

template<int F>
__global__ __launch_bounds__(256) void aggregate_ws(
    const u16* __restrict__ XW, const int* __restrict__ rowstart,
    const int* __restrict__ csr_src, const float* __restrict__ dis,
    const u16* __restrict__ bias, const u16* __restrict__ aptr,
    u16* __restrict__ out, int N, int* __restrict__ ticket)
{
    using V = typename AggVec<F>::T;
    constexpr int EPL = AggVec<F>::EPL;
    int lane = threadIdx.x & 63;
    int tf = lane * EPL;
    float a = bf2f(aptr[0]);
    for (;;){
        int base = 0;
        if (lane == 0) base = atomicAdd(ticket, 4);
        base = __shfl(base, 0, 64);
        if (base >= N) return;
        int nend = (base + 4 < N) ? base + 4 : N;
        for (int node = base; node < nend; node++){
            float di = dis[node];
            int e0 = rowstart[node], e1 = rowstart[node + 1];
            float acc[EPL];
            #pragma unroll
            for (int j = 0; j < EPL; j++) acc[j] = 0.f;
            int e = e0;
            for (; e + 8 <= e1; e += 8){
                int si[8]; float ci[8]; V vi[8];
                #pragma unroll
                for (int u = 0; u < 8; u++) si[u] = csr_src[e + u];
                #pragma unroll
                for (int u = 0; u < 8; u++) ci[u] = dis[si[u]];
                #pragma unroll
                for (int u = 0; u < 8; u++)
                    vi[u] = *(const V*)(XW + (size_t)si[u] * F + tf);
                #pragma unroll
                for (int u = 0; u < 8; u++)
                    #pragma unroll
                    for (int j = 0; j < EPL; j++)
                        acc[j] += ci[u] * bf2f((u16)vi[u][j]);
            }
            for (; e + 4 <= e1; e += 4){
                int s0 = csr_src[e], s1 = csr_src[e+1], s2 = csr_src[e+2], s3 = csr_src[e+3];
                float c0 = dis[s0], c1 = dis[s1], c2 = dis[s2], c3 = dis[s3];
                V v0 = *(const V*)(XW + (size_t)s0 * F + tf);
                V v1 = *(const V*)(XW + (size_t)s1 * F + tf);
                V v2 = *(const V*)(XW + (size_t)s2 * F + tf);
                V v3 = *(const V*)(XW + (size_t)s3 * F + tf);
                #pragma unroll
                for (int j = 0; j < EPL; j++)
                    acc[j] += c0*bf2f((u16)v0[j]) + c1*bf2f((u16)v1[j])
                            + c2*bf2f((u16)v2[j]) + c3*bf2f((u16)v3[j]);
            }
            for (; e < e1; e++){
                int s = csr_src[e];
                float c = dis[s];
                V v = *(const V*)(XW + (size_t)s * F + tf);
                #pragma unroll
                for (int j = 0; j < EPL; j++) acc[j] += c * bf2f((u16)v[j]);
            }
            {   // self-loop
                V v = *(const V*)(XW + (size_t)node * F + tf);
                #pragma unroll
                for (int j = 0; j < EPL; j++) acc[j] += di * bf2f((u16)v[j]);
            }
            V bv = *(const V*)(bias + tf);
            V o;
            #pragma unroll
            for (int j = 0; j < EPL; j++){
                float x = di * acc[j] + bf2f((u16)bv[j]);
                x = (x > 0.f) ? x : a * x;
                o[j] = (short)f2bf(x);
            }
            *(V*)(out + (size_t)node * F + tf) = o;
        }
    }
}

// ---------------- launch ----------------------------------------------------
extern "C" void kernel_launch(void* const* d_in, const int* in_sizes, int n_in,
                              void* d_out, int out_size, void* d_ws, size_t ws_size,
                              hipStream_t stream)
{
    int iX=0, iEI=1, iW1=2, ib1=3, iW2=4, ib2=5, ia=6, iW3=7, ib3=8, iW4=9, ib4=10;
    {
        int jX=-1,jEI=-1,jW1=-1,jb1=-1,jW2=-1,ja=-1,jW3=-1,jW4=-1,jb2=-1,jb3=-1,jb4=-1;
        int n64k=0, n256=0;
        for (int i = 0; i < n_in; i++){
            switch (in_sizes[i]){
                case 10240000: jX = i; break;
                case 640000:   jEI = i; break;
                case 262144:   jW1 = i; break;
                case 131072:   jW2 = i; break;
                case 512:      jb1 = i; break;
                case 1:        ja = i; break;
                case 65536:    if (n64k++ == 0) jW3 = i; else jW4 = i; break;
                case 256: {
                    int k = n256++;
                    if (k == 0) jb2 = i; else if (k == 1) jb3 = i; else jb4 = i;
                } break;
                default: break;
            }
        }
        if (jX>=0&&jEI>=0&&jW1>=0&&jb1>=0&&jW2>=0&&ja>=0&&jW3>=0&&jW4>=0&&jb2>=0&&jb3>=0&&jb4>=0){
            iX=jX; iEI=jEI; iW1=jW1; ib1=jb1; iW2=jW2; ib2=jb2; ia=ja; iW3=jW3; ib3=jb3; iW4=jW4; ib4=jb4;
        }
    }
    int N = in_sizes[iX] / 512;
    int E = in_sizes[iEI] / 2;
    const int* EI = (const int*)d_in[iEI];
    float* OUT = (float*)d_out;                 // fp32 output (N*256*4 bytes)
    u16*   S   = (u16*)d_out;                   // same bytes as bf16 N x 512 scratch

    char* ws = (char*)d_ws;
    size_t off = 0;
    auto alloc = [&](size_t bytes)->char*{
        char* p = ws + off;
        off = (off + bytes + 255) & ~(size_t)255;
        return p;
    };
    int nb = (N + 255) / 256;                   // scan blocks (N<=32768)
    int*   cnt  = (int*)  alloc((size_t)N*4);
    int*   incl = (int*)  alloc((size_t)N*4);
    int*   bsum = (int*)  alloc(512);
    int*   boff = (int*)  alloc(512);
    int*   efmt = (int*)  alloc(4);
    int*   f32f = (int*)  alloc(4);
    int*   zf   = (int*)  alloc(4);
    int*   tk1  = (int*)  alloc(4);
    int*   tk2  = (int*)  alloc(4);
    float* dis  = (float*)alloc((size_t)N*4);
    int*   rs   = (int*)  alloc((size_t)(N+1)*4);
    int*   cur  = (int*)  alloc((size_t)N*4);
    int*   csr  = (int*)  alloc((size_t)E*4);
    u16*   WT1  = (u16*)  alloc((size_t)512*512*2);
    u16*   WT2  = (u16*)  alloc((size_t)256*512*2);
    u16*   WT3  = (u16*)  alloc((size_t)256*256*2);
    u16*   WT4  = (u16*)  alloc((size_t)256*256*2);
    u16*   b1c  = (u16*)  alloc((size_t)512*2);
    u16*   b2c  = (u16*)  alloc((size_t)256*2);
    u16*   b3c  = (u16*)  alloc((size_t)256*2);
    u16*   b4c  = (u16*)  alloc((size_t)256*2);
    u16*   ac   = (u16*)  alloc((size_t)8*2);
    u16*   h1   = (u16*)  alloc((size_t)N*512*2);   // 20.48 MB
    u16*   P    = (u16*)  alloc((size_t)N*256*2);   // 10.24 MB

    if (ws_size < off) return;

    hipMemsetAsync(cnt, 0, (size_t)N*4, stream);
    probe_all<<<1, 256, 0, stream>>>((const u16*)d_in[iW1], EI,
                                     d_in[ib1], d_in[ib2], d_in[ib3], d_in[ib4],
                                     d_in[ia], f32f, efmt, zf, tk1, tk2,
                                     b1c, b2c, b3c, b4c, ac);

    int egrid = (E + 255) / 256;
    deg_count<<<egrid, 256, 0, stream>>>(EI, efmt, cnt, E, N);
    scan1<<<nb, 256, 0, stream>>>(cnt, incl, bsum, N);
    scan2<<<1, 128, 0, stream>>>(bsum, boff, nb, rs + N);
    scan3<<<nb, 256, 0, stream>>>(cnt, incl, boff, rs, cur, dis, N);
    csr_fill<<<egrid, 256, 0, stream>>>(EI, efmt, cur, csr, E, N);

    // all weight transposes in one launch
    transpose_all<<<dim3(16, 16, 4), dim3(32, 8), 0, stream>>>(
        d_in[iW1], d_in[iW2], d_in[iW3], d_in[iW4], f32f, WT1, WT2, WT3, WT4);

    int gm = (N + TM - 1) / TM;           // 313
    dim3 g512(gm, 512 / TN);              // 1252 blocks
    dim3 g256(gm, 256 / TN);              //  626 blocks
    int agrid = 1024;                     // 4096 waves, ticket-fed

    // layer 1: full-width XW1 -> S (bf16 scratch in OUT buffer)
    gemm_mfma<0,0><<<g512, 256, 0, stream>>>(d_in[iX], f32f, WT1, nullptr, S, N, 512, 512);
    aggregate_ws<512><<<agrid, 256, 0, stream>>>(S, rs, csr, dis, b1c, ac, h1, N, tk1);

    // layer 2: h1 @ W2 -> P ; aggregate -> Q (OUT bytes as bf16; S dead)
    u16* Q = (u16*)d_out;
    gemm_mfma<0,0><<<g256, 256, 0, stream>>>(h1, zf, WT2, nullptr, P, N, 512, 256);
    aggregate_ws<256><<<agrid, 256, 0, stream>>>(P, rs, csr, dis, b2c, ac, Q, N, tk2);

    // projection MLP: ELU(Q @ W3 + b3) -> P ; P @ W4 + b4 -> OUT (fp32)
    gemm_mfma<2,0><<<g256, 256, 0, stream>>>(Q, zf, WT3, b3c, P, N, 256, 256);
    gemm_mfma<1,1><<<g256, 256, 0, stream>>>(P, zf, WT4, b4c, OUT, N, 256, 256);
}

// Round 17
// 287.727 us; speedup vs baseline: 1.6387x; 1.6387x over previous
//
#include <hip/hip_runtime.h>

typedef unsigned short u16;
typedef unsigned int   u32;
typedef __attribute__((ext_vector_type(8))) short short8;
typedef __attribute__((ext_vector_type(4))) float f32x4;

__device__ __forceinline__ float bf2f(u16 h){
    return __uint_as_float(((u32)h) << 16);
}
__device__ __forceinline__ u16 f2bf(float f){
    u32 u = __float_as_uint(f);
    u += 0x7fffu + ((u >> 16) & 1u);   // RNE
    return (u16)(u >> 16);
}

// ---- one-block probe: dtype flags + all small-tensor conversions ----------
__global__ void probe_all(const u16* __restrict__ w1, const int* __restrict__ ei,
                          const void* b1, const void* b2, const void* b3,
                          const void* b4, const void* av,
                          int* __restrict__ f32f, int* __restrict__ efmt,
                          int* __restrict__ zf,
                          u16* d1, u16* d2, u16* d3, u16* d4, u16* da){
    __shared__ int sf32, sfmt;
    int t = threadIdx.x;                 // 256
    if (t == 0){ sf32 = 0; sfmt = 0; }
    __syncthreads();
    {   // fp32-vs-bf16 probe on W1 (~N(0,0.02)): bf16 never has |v|>=1
        int huge = 0;
        #pragma unroll
        for (int k = 0; k < 16; k++){
            u16 h = w1[t * 16 + k];
            if (((h >> 7) & 0xFF) >= 0x7F) huge = 1;
        }
        if (huge) atomicOr(&sf32, 1);
    }
    if (ei[2*t + 1] != 0) atomicOr(&sfmt, 1);   // int64 => odd words zero
    __syncthreads();
    int f32 = sf32, fmt = sfmt;
    if (t == 0){ f32f[0] = f32; efmt[0] = fmt; zf[0] = 0; }
    #define CV(s,i) (f32 ? f2bf(((const float*)(s))[i]) : ((const u16*)(s))[i])
    d1[t]       = CV(b1, t);
    d1[t + 256] = CV(b1, t + 256);
    d2[t] = CV(b2, t);
    d3[t] = CV(b3, t);
    d4[t] = CV(b4, t);
    if (t == 0) da[0] = CV(av, 0);
    #undef CV
}

// (2,E) block layout per jax: src = row0, dst = row1
__device__ __forceinline__ int eload(const int* ei, int fmt, int idx){
    return fmt ? ei[idx] : ei[2*idx];    // int64 little-endian: low word
}

// ---------------- degree / CSR build (dst-keyed) ---------------------------
__global__ void deg_count(const int* __restrict__ ei, const int* __restrict__ efmt,
                          int* __restrict__ cnt, int E, int N){
    int e = blockIdx.x * 256 + threadIdx.x;
    if (e < E){
        int d = eload(ei, efmt[0], E + e);
        if ((unsigned)d < (unsigned)N) atomicAdd(&cnt[d], 1);
    }
}

__global__ void scan1(const int* __restrict__ cnt, int* __restrict__ incl,
                      int* __restrict__ bsum, int N){
    __shared__ int s[256];
    int t = threadIdx.x, i = blockIdx.x * 256 + t;
    int v = (i < N) ? cnt[i] : 0;
    s[t] = v;
    __syncthreads();
    #pragma unroll
    for (int off = 1; off < 256; off <<= 1){
        int u = (t >= off) ? s[t - off] : 0;
        __syncthreads();
        s[t] += u;
        __syncthreads();
    }
    if (i < N) incl[i] = s[t];
    if (t == 255) bsum[blockIdx.x] = s[255];
}

__global__ void scan2(const int* __restrict__ bsum, int* __restrict__ boff,
                      int nb, int* __restrict__ rowstart_last){
    __shared__ int s[128];
    int t = threadIdx.x;
    int v = (t < nb) ? bsum[t] : 0;
    s[t] = v;
    __syncthreads();
    #pragma unroll
    for (int off = 1; off < 128; off <<= 1){
        int u = (t >= off) ? s[t - off] : 0;
        __syncthreads();
        s[t] += u;
        __syncthreads();
    }
    if (t < nb) boff[t] = s[t] - v;
    if (t == nb - 1) rowstart_last[0] = s[t];
}

__global__ void scan3(const int* __restrict__ cnt, const int* __restrict__ incl,
                      const int* __restrict__ boff, int* __restrict__ rowstart,
                      int* __restrict__ cursor, float* __restrict__ dis, int N){
    int i = blockIdx.x * 256 + threadIdx.x;
    if (i < N){
        int v = cnt[i];
        int rsv = boff[blockIdx.x] + incl[i] - v;
        rowstart[i] = rsv;
        cursor[i]   = rsv;
        dis[i] = rsqrtf((float)v + 1.0f);
    }
}

__global__ void csr_fill(const int* __restrict__ ei, const int* __restrict__ efmt,
                         int* __restrict__ cursor, int* __restrict__ csr_src,
                         int E, int N){
    int e = blockIdx.x * 256 + threadIdx.x;
    if (e < E){
        int fmt = efmt[0];
        int d = eload(ei, fmt, E + e);
        if ((unsigned)d < (unsigned)N){
            int p = atomicAdd(&cursor[d], 1);
            csr_src[p] = eload(ei, fmt, e);
        }
    }
}

// -------- all 4 weights: convert+transpose in ONE launch -------------------
__global__ void transpose_all(const void* w1, const void* w2, const void* w3,
                              const void* w4, const int* __restrict__ flag,
                              u16* o1, u16* o2, u16* o3, u16* o4){
    const void* in; u16* out; int K, N;
    switch (blockIdx.z){
        case 0:  in = w1; out = o1; K = 512; N = 512; break;
        case 1:  in = w2; out = o2; K = 512; N = 256; break;
        case 2:  in = w3; out = o3; K = 256; N = 256; break;
        default: in = w4; out = o4; K = 256; N = 256; break;
    }
    int bx = blockIdx.x * 32;   // n
    int by = blockIdx.y * 32;   // k
    if (bx >= N || by >= K) return;
    __shared__ u16 t[32][33];
    int x = threadIdx.x, y = threadIdx.y;   // (32,8)
    int f32 = flag[0];
    #pragma unroll
    for (int i = 0; i < 32; i += 8){
        size_t idx = (size_t)(by + y + i) * N + bx + x;
        t[y + i][x] = f32 ? f2bf(((const float*)in)[idx]) : ((const u16*)in)[idx];
    }
    __syncthreads();
    #pragma unroll
    for (int i = 0; i < 32; i += 8)
        out[(size_t)(bx + y + i) * K + by + x] = t[x][y + i];
}

// ---------------- MFMA GEMM: C[M][N] = A[M][K] * BT[N][K]^T ----------------
// 64x128 tile, 256 thr = 4 waves (2x2), each wave 32x64 = 2x4 16x16 frags.
#define TM 64
#define TN 128
#define BK 32
#define BKP 40   // padded LDS row

template<int MODE, int OUTF>   // MODE: 0 plain,1 +bias,2 +bias+ELU; OUTF: 0 bf16,1 fp32
__global__ __launch_bounds__(256) void gemm_mfma(
    const void* __restrict__ A, const int* __restrict__ af32,
    const u16* __restrict__ BT,
    const u16* __restrict__ bias, void* __restrict__ Cv,
    int M, int K, int N)
{
    __shared__ __align__(16) u16 As[TM * BKP];
    __shared__ __align__(16) u16 Bs[TN * BKP];
    int tid  = threadIdx.x;
    int lane = tid & 63;
    int wave = tid >> 6;
    int waveM = wave >> 1, waveN = wave & 1;
    int bm = blockIdx.x * TM;
    int bn = blockIdx.y * TN;
    int f32 = af32[0];

    f32x4 acc[2][4] = {};

    int alr = tid >> 2;            // A: 0..63 row, 4 thr/row
    int alc = (tid & 3) * 8;
    int blr = tid >> 1;            // B: 0..127 row, 2 thr/row
    int blc = (tid & 1) * 16;

    for (int k0 = 0; k0 < K; k0 += BK){
        {   // A tile 64x32 (M-guarded)
            int gr = bm + alr;
            short8 v = {0,0,0,0,0,0,0,0};
            if (gr < M){
                if (f32){
                    const float* p = (const float*)A + (size_t)gr * K + k0 + alc;
                    f32x4 a0 = *(const f32x4*)p;
                    f32x4 a1 = *(const f32x4*)(p + 4);
                    #pragma unroll
                    for (int j = 0; j < 4; j++){
                        v[j]   = (short)f2bf(a0[j]);
                        v[4+j] = (short)f2bf(a1[j]);
                    }
                } else {
                    v = *(const short8*)((const u16*)A + (size_t)gr * K + k0 + alc);
                }
            }
            *(short8*)&As[alr * BKP + alc] = v;
        }
        {   // B tile 128x32 from WT[N][K]
            const u16* p = BT + (size_t)(bn + blr) * K + k0 + blc;
            short8 v0 = *(const short8*)p;
            short8 v1 = *(const short8*)(p + 8);
            *(short8*)&Bs[blr * BKP + blc]     = v0;
            *(short8*)&Bs[blr * BKP + blc + 8] = v1;
        }
        __syncthreads();
        int q = lane >> 4;
        int r16 = lane & 15;
        short8 af[2], bfr[4];
        #pragma unroll
        for (int i = 0; i < 2; i++)
            af[i]  = *(const short8*)&As[(waveM*32 + i*16 + r16) * BKP + q*8];
        #pragma unroll
        for (int j = 0; j < 4; j++)
            bfr[j] = *(const short8*)&Bs[(waveN*64 + j*16 + r16) * BKP + q*8];
        #pragma unroll
        for (int i = 0; i < 2; i++)
            #pragma unroll
            for (int j = 0; j < 4; j++)
                acc[i][j] = __builtin_amdgcn_mfma_f32_16x16x32_bf16(af[i], bfr[j], acc[i][j], 0, 0, 0);
        __syncthreads();
    }

    int q = lane >> 4;
    int c16 = lane & 15;
    #pragma unroll
    for (int i = 0; i < 2; i++){
        #pragma unroll
        for (int j = 0; j < 4; j++){
            int gcol = bn + waveN*64 + j*16 + c16;
            float bvv = (MODE >= 1) ? bf2f(bias[gcol]) : 0.f;
            #pragma unroll
            for (int r = 0; r < 4; r++){
                int grow = bm + waveM*32 + i*16 + q*4 + r;
                if (grow < M){
                    float v = acc[i][j][r] + bvv;
                    if (MODE == 2) v = (v > 0.f) ? v : expm1f(v);
                    if (OUTF) ((float*)Cv)[(size_t)grow * N + gcol] = v;
                    else      ((u16*)Cv)[(size_t)grow * N + gcol] = f2bf(v);
                }
            }
        }
    }
}

// ---------------- pull aggregation (+bias+PReLU), F features ---------------
// Static blocked layout (R15-proven): NPB nodes/block, F/8 lanes x 8 feats.
// out = prelu( di*( sum_e dis[s_e]*row_e + di*row_self ) + bias )
template<int F, int NPB>
__global__ __launch_bounds__(F/8*NPB) void aggregate(
    const u16* __restrict__ XW, const int* __restrict__ rowstart,
    const int* __restrict__ csr_src, const float* __restrict__ dis,
    const u16* __restrict__ bias, const u16* __restrict__ aptr,
    u16* __restrict__ out, int N)
{
    int node = blockIdx.x * NPB + threadIdx.y;
    if (node >= N) return;
    int tf = threadIdx.x * 8;
    float a  = bf2f(aptr[0]);
    float di = dis[node];
    int e0 = rowstart[node], e1 = rowstart[node + 1];
    float acc[8] = {0,0,0,0,0,0,0,0};
    int e = e0;
    for (; e + 8 <= e1; e += 8){
        int   si[8];
        float ci[8];
        short8 vi[8];
        #pragma unroll
        for (int u = 0; u < 8; u++) si[u] = csr_src[e + u];
        #pragma unroll
        for (int u = 0; u < 8; u++) ci[u] = dis[si[u]];
        #pragma unroll
        for (int u = 0; u < 8; u++)
            vi[u] = *(const short8*)(XW + (size_t)si[u] * F + tf);
        #pragma unroll
        for (int u = 0; u < 8; u++)
            #pragma unroll
            for (int j = 0; j < 8; j++)
                acc[j] += ci[u] * bf2f((u16)vi[u][j]);
    }
    for (; e + 4 <= e1; e += 4){
        int s0 = csr_src[e], s1 = csr_src[e+1], s2 = csr_src[e+2], s3 = csr_src[e+3];
        float c0 = dis[s0], c1 = dis[s1], c2 = dis[s2], c3 = dis[s3];
        short8 v0 = *(const short8*)(XW + (size_t)s0 * F + tf);
        short8 v1 = *(const short8*)(XW + (size_t)s1 * F + tf);
        short8 v2 = *(const short8*)(XW + (size_t)s2 * F + tf);
        short8 v3 = *(const short8*)(XW + (size_t)s3 * F + tf);
        #pragma unroll
        for (int j = 0; j < 8; j++)
            acc[j] += c0*bf2f((u16)v0[j]) + c1*bf2f((u16)v1[j])
                    + c2*bf2f((u16)v2[j]) + c3*bf2f((u16)v3[j]);
    }
    for (; e < e1; e++){
        int s = csr_src[e];
        float c = dis[s];
        short8 v = *(const short8*)(XW + (size_t)s * F + tf);
        #pragma unroll
        for (int j = 0; j < 8; j++) acc[j] += c * bf2f((u16)v[j]);
    }
    {   // self-loop
        short8 v = *(const short8*)(XW + (size_t)node * F + tf);
        #pragma unroll
        for (int j = 0; j < 8; j++) acc[j] += di * bf2f((u16)v[j]);
    }
    short8 bv = *(const short8*)(bias + tf);
    short8 o;
    #pragma unroll
    for (int j = 0; j < 8; j++){
        float x = di * acc[j] + bf2f((u16)bv[j]);
        x = (x > 0.f) ? x : a * x;
        o[j] = (short)f2bf(x);
    }
    *(short8*)(out + (size_t)node * F + tf) = o;
}

// ---------------- launch ----------------------------------------------------
extern "C" void kernel_launch(void* const* d_in, const int* in_sizes, int n_in,
                              void* d_out, int out_size, void* d_ws, size_t ws_size,
                              hipStream_t stream)
{
    int iX=0, iEI=1, iW1=2, ib1=3, iW2=4, ib2=5, ia=6, iW3=7, ib3=8, iW4=9, ib4=10;
    {
        int jX=-1,jEI=-1,jW1=-1,jb1=-1,jW2=-1,ja=-1,jW3=-1,jW4=-1,jb2=-1,jb3=-1,jb4=-1;
        int n64k=0, n256=0;
        for (int i = 0; i < n_in; i++){
            switch (in_sizes[i]){
                case 10240000: jX = i; break;
                case 640000:   jEI = i; break;
                case 262144:   jW1 = i; break;
                case 131072:   jW2 = i; break;
                case 512:      jb1 = i; break;
                case 1:        ja = i; break;
                case 65536:    if (n64k++ == 0) jW3 = i; else jW4 = i; break;
                case 256: {
                    int k = n256++;
                    if (k == 0) jb2 = i; else if (k == 1) jb3 = i; else jb4 = i;
                } break;
                default: break;
            }
        }
        if (jX>=0&&jEI>=0&&jW1>=0&&jb1>=0&&jW2>=0&&ja>=0&&jW3>=0&&jW4>=0&&jb2>=0&&jb3>=0&&jb4>=0){
            iX=jX; iEI=jEI; iW1=jW1; ib1=jb1; iW2=jW2; ib2=jb2; ia=ja; iW3=jW3; ib3=jb3; iW4=jW4; ib4=jb4;
        }
    }
    int N = in_sizes[iX] / 512;
    int E = in_sizes[iEI] / 2;
    const int* EI = (const int*)d_in[iEI];
    float* OUT = (float*)d_out;                 // fp32 output (N*256*4 bytes)
    u16*   S   = (u16*)d_out;                   // same bytes as bf16 N x 512 scratch

    char* ws = (char*)d_ws;
    size_t off = 0;
    auto alloc = [&](size_t bytes)->char*{
        char* p = ws + off;
        off = (off + bytes + 255) & ~(size_t)255;
        return p;
    };
    int nb = (N + 255) / 256;                   // scan blocks (N<=32768)
    int*   cnt  = (int*)  alloc((size_t)N*4);
    int*   incl = (int*)  alloc((size_t)N*4);
    int*   bsum = (int*)  alloc(512);
    int*   boff = (int*)  alloc(512);
    int*   efmt = (int*)  alloc(4);
    int*   f32f = (int*)  alloc(4);
    int*   zf   = (int*)  alloc(4);
    float* dis  = (float*)alloc((size_t)N*4);
    int*   rs   = (int*)  alloc((size_t)(N+1)*4);
    int*   cur  = (int*)  alloc((size_t)N*4);
    int*   csr  = (int*)  alloc((size_t)E*4);
    u16*   WT1  = (u16*)  alloc((size_t)512*512*2);
    u16*   WT2  = (u16*)  alloc((size_t)256*512*2);
    u16*   WT3  = (u16*)  alloc((size_t)256*256*2);
    u16*   WT4  = (u16*)  alloc((size_t)256*256*2);
    u16*   b1c  = (u16*)  alloc((size_t)512*2);
    u16*   b2c  = (u16*)  alloc((size_t)256*2);
    u16*   b3c  = (u16*)  alloc((size_t)256*2);
    u16*   b4c  = (u16*)  alloc((size_t)256*2);
    u16*   ac   = (u16*)  alloc((size_t)8*2);
    u16*   h1   = (u16*)  alloc((size_t)N*512*2);   // 20.48 MB
    u16*   P    = (u16*)  alloc((size_t)N*256*2);   // 10.24 MB

    if (ws_size < off) return;

    hipMemsetAsync(cnt, 0, (size_t)N*4, stream);
    probe_all<<<1, 256, 0, stream>>>((const u16*)d_in[iW1], EI,
                                     d_in[ib1], d_in[ib2], d_in[ib3], d_in[ib4],
                                     d_in[ia], f32f, efmt, zf,
                                     b1c, b2c, b3c, b4c, ac);

    int egrid = (E + 255) / 256;
    deg_count<<<egrid, 256, 0, stream>>>(EI, efmt, cnt, E, N);
    scan1<<<nb, 256, 0, stream>>>(cnt, incl, bsum, N);
    scan2<<<1, 128, 0, stream>>>(bsum, boff, nb, rs + N);
    scan3<<<nb, 256, 0, stream>>>(cnt, incl, boff, rs, cur, dis, N);
    csr_fill<<<egrid, 256, 0, stream>>>(EI, efmt, cur, csr, E, N);

    // all weight transposes in one launch
    transpose_all<<<dim3(16, 16, 4), dim3(32, 8), 0, stream>>>(
        d_in[iW1], d_in[iW2], d_in[iW3], d_in[iW4], f32f, WT1, WT2, WT3, WT4);

    int gm = (N + TM - 1) / TM;           // 313
    dim3 g512(gm, 512 / TN);              // 1252 blocks
    dim3 g256(gm, 256 / TN);              //  626 blocks

    // layer 1: full-width XW1 -> S (bf16 scratch in OUT buffer)
    gemm_mfma<0,0><<<g512, 256, 0, stream>>>(d_in[iX], f32f, WT1, nullptr, S, N, 512, 512);
    aggregate<512,2><<<(N+1)/2, dim3(64,2), 0, stream>>>(S, rs, csr, dis, b1c, ac, h1, N);

    // layer 2: h1 @ W2 -> P ; aggregate -> Q (OUT bytes as bf16; S dead)
    u16* Q = (u16*)d_out;
    gemm_mfma<0,0><<<g256, 256, 0, stream>>>(h1, zf, WT2, nullptr, P, N, 512, 256);
    aggregate<256,4><<<(N+3)/4, dim3(32,4), 0, stream>>>(P, rs, csr, dis, b2c, ac, Q, N);

    // projection MLP: ELU(Q @ W3 + b3) -> P ; P @ W4 + b4 -> OUT (fp32)
    gemm_mfma<2,0><<<g256, 256, 0, stream>>>(Q, zf, WT3, b3c, P, N, 256, 256);
    gemm_mfma<1,1><<<g256, 256, 0, stream>>>(P, zf, WT4, b4c, OUT, N, 256, 256);
}

// Round 18
// 285.407 us; speedup vs baseline: 1.6520x; 1.0081x over previous
//
#include <hip/hip_runtime.h>

typedef unsigned short u16;
typedef unsigned int   u32;
typedef __attribute__((ext_vector_type(8))) short short8;
typedef __attribute__((ext_vector_type(4))) float f32x4;

__device__ __forceinline__ float bf2f(u16 h){
    return __uint_as_float(((u32)h) << 16);
}
__device__ __forceinline__ u16 f2bf(float f){
    u32 u = __float_as_uint(f);
    u += 0x7fffu + ((u >> 16) & 1u);   // RNE
    return (u16)(u >> 16);
}

// ---- one-block probe: dtype flags + small tensors + cnt zeroing -----------
__global__ void probe_all(const u16* __restrict__ w1, const int* __restrict__ ei,
                          const void* b1, const void* b2, const void* b3,
                          const void* b4, const void* av,
                          int* __restrict__ f32f, int* __restrict__ efmt,
                          int* __restrict__ zf, int* __restrict__ cnt, int N,
                          u16* d1, u16* d2, u16* d3, u16* d4, u16* da){
    __shared__ int sf32, sfmt;
    int t = threadIdx.x;                 // 256
    if (t == 0){ sf32 = 0; sfmt = 0; }
    __syncthreads();
    for (int i = t; i < N; i += 256) cnt[i] = 0;
    {   // fp32-vs-bf16 probe on W1 (~N(0,0.02)): bf16 never has |v|>=1
        int huge = 0;
        #pragma unroll
        for (int k = 0; k < 16; k++){
            u16 h = w1[t * 16 + k];
            if (((h >> 7) & 0xFF) >= 0x7F) huge = 1;
        }
        if (huge) atomicOr(&sf32, 1);
    }
    if (ei[2*t + 1] != 0) atomicOr(&sfmt, 1);   // int64 => odd words zero
    __syncthreads();
    int f32 = sf32, fmt = sfmt;
    if (t == 0){ f32f[0] = f32; efmt[0] = fmt; zf[0] = 0; }
    #define CV(s,i) (f32 ? f2bf(((const float*)(s))[i]) : ((const u16*)(s))[i])
    d1[t]       = CV(b1, t);
    d1[t + 256] = CV(b1, t + 256);
    d2[t] = CV(b2, t);
    d3[t] = CV(b3, t);
    d4[t] = CV(b4, t);
    if (t == 0) da[0] = CV(av, 0);
    #undef CV
}

// (2,E) block layout per jax: src = row0, dst = row1
__device__ __forceinline__ int eload(const int* ei, int fmt, int idx){
    return fmt ? ei[idx] : ei[2*idx];    // int64 little-endian: low word
}

// ---------------- degree / CSR build (dst-keyed) ---------------------------
__global__ void deg_count(const int* __restrict__ ei, const int* __restrict__ efmt,
                          int* __restrict__ cnt, int E, int N){
    int e = blockIdx.x * 256 + threadIdx.x;
    if (e < E){
        int d = eload(ei, efmt[0], E + e);
        if ((unsigned)d < (unsigned)N) atomicAdd(&cnt[d], 1);
    }
}

__global__ void scan1(const int* __restrict__ cnt, int* __restrict__ incl,
                      int* __restrict__ bsum, int N){
    __shared__ int s[256];
    int t = threadIdx.x, i = blockIdx.x * 256 + t;
    int v = (i < N) ? cnt[i] : 0;
    s[t] = v;
    __syncthreads();
    #pragma unroll
    for (int off = 1; off < 256; off <<= 1){
        int u = (t >= off) ? s[t - off] : 0;
        __syncthreads();
        s[t] += u;
        __syncthreads();
    }
    if (i < N) incl[i] = s[t];
    if (t == 255) bsum[blockIdx.x] = s[255];
}

// merged scan2+scan3: each block redundantly scans the <=128 block sums
__global__ void scan23(const int* __restrict__ cnt, const int* __restrict__ incl,
                       const int* __restrict__ bsum, int nb,
                       int* __restrict__ rowstart, int* __restrict__ cursor,
                       float* __restrict__ dis, int N){
    __shared__ int s[128];
    int t = threadIdx.x;   // 256
    if (t < 128) s[t] = (t < nb) ? bsum[t] : 0;
    __syncthreads();
    #pragma unroll
    for (int off = 1; off < 128; off <<= 1){
        int u = 0;
        if (t < 128 && t >= off) u = s[t - off];
        __syncthreads();
        if (t < 128) s[t] += u;
        __syncthreads();
    }
    int boffb = s[blockIdx.x] - bsum[blockIdx.x];   // exclusive prefix for this block
    int i = blockIdx.x * 256 + t;
    if (i < N){
        int v = cnt[i];
        int rsv = boffb + incl[i] - v;
        rowstart[i] = rsv;
        cursor[i]   = rsv;
        dis[i] = rsqrtf((float)v + 1.0f);
    }
    if (blockIdx.x == 0 && t == 0) rowstart[N] = s[nb - 1];
}

__global__ void csr_fill(const int* __restrict__ ei, const int* __restrict__ efmt,
                         int* __restrict__ cursor, int* __restrict__ csr_src,
                         int E, int N){
    int e = blockIdx.x * 256 + threadIdx.x;
    if (e < E){
        int fmt = efmt[0];
        int d = eload(ei, fmt, E + e);
        if ((unsigned)d < (unsigned)N){
            int p = atomicAdd(&cursor[d], 1);
            csr_src[p] = eload(ei, fmt, e);
        }
    }
}

// -------- all 4 weights: convert+transpose in ONE launch -------------------
__global__ void transpose_all(const void* w1, const void* w2, const void* w3,
                              const void* w4, const int* __restrict__ flag,
                              u16* o1, u16* o2, u16* o3, u16* o4){
    const void* in; u16* out; int K, N;
    switch (blockIdx.z){
        case 0:  in = w1; out = o1; K = 512; N = 512; break;
        case 1:  in = w2; out = o2; K = 512; N = 256; break;
        case 2:  in = w3; out = o3; K = 256; N = 256; break;
        default: in = w4; out = o4; K = 256; N = 256; break;
    }
    int bx = blockIdx.x * 32;   // n
    int by = blockIdx.y * 32;   // k
    if (bx >= N || by >= K) return;
    __shared__ u16 t[32][33];
    int x = threadIdx.x, y = threadIdx.y;   // (32,8)
    int f32 = flag[0];
    #pragma unroll
    for (int i = 0; i < 32; i += 8){
        size_t idx = (size_t)(by + y + i) * N + bx + x;
        t[y + i][x] = f32 ? f2bf(((const float*)in)[idx]) : ((const u16*)in)[idx];
    }
    __syncthreads();
    #pragma unroll
    for (int i = 0; i < 32; i += 8)
        out[(size_t)(bx + y + i) * K + by + x] = t[x][y + i];
}

// ---------------- MFMA GEMM: C[M][N] = A[M][K] * BT[N][K]^T ----------------
// 64x128 tile, 256 thr = 4 waves (2x2), each wave 32x64 = 2x4 16x16 frags.
#define TM 64
#define TN 128
#define BK 32
#define BKP 40   // padded LDS row

template<int MODE, int OUTF>   // MODE: 0 plain,1 +bias,2 +bias+ELU; OUTF: 0 bf16,1 fp32
__global__ __launch_bounds__(256) void gemm_mfma(
    const void* __restrict__ A, const int* __restrict__ af32,
    const u16* __restrict__ BT,
    const u16* __restrict__ bias, void* __restrict__ Cv,
    int M, int K, int N)
{
    __shared__ __align__(16) u16 As[TM * BKP];
    __shared__ __align__(16) u16 Bs[TN * BKP];
    int tid  = threadIdx.x;
    int lane = tid & 63;
    int wave = tid >> 6;
    int waveM = wave >> 1, waveN = wave & 1;
    int bm = blockIdx.x * TM;
    int bn = blockIdx.y * TN;
    int f32 = af32[0];

    f32x4 acc[2][4] = {};

    int alr = tid >> 2;            // A: 0..63 row, 4 thr/row
    int alc = (tid & 3) * 8;
    int blr = tid >> 1;            // B: 0..127 row, 2 thr/row
    int blc = (tid & 1) * 16;

    for (int k0 = 0; k0 < K; k0 += BK){
        {   // A tile 64x32 (M-guarded)
            int gr = bm + alr;
            short8 v = {0,0,0,0,0,0,0,0};
            if (gr < M){
                if (f32){
                    const float* p = (const float*)A + (size_t)gr * K + k0 + alc;
                    f32x4 a0 = *(const f32x4*)p;
                    f32x4 a1 = *(const f32x4*)(p + 4);
                    #pragma unroll
                    for (int j = 0; j < 4; j++){
                        v[j]   = (short)f2bf(a0[j]);
                        v[4+j] = (short)f2bf(a1[j]);
                    }
                } else {
                    v = *(const short8*)((const u16*)A + (size_t)gr * K + k0 + alc);
                }
            }
            *(short8*)&As[alr * BKP + alc] = v;
        }
        {   // B tile 128x32 from WT[N][K]
            const u16* p = BT + (size_t)(bn + blr) * K + k0 + blc;
            short8 v0 = *(const short8*)p;
            short8 v1 = *(const short8*)(p + 8);
            *(short8*)&Bs[blr * BKP + blc]     = v0;
            *(short8*)&Bs[blr * BKP + blc + 8] = v1;
        }
        __syncthreads();
        int q = lane >> 4;
        int r16 = lane & 15;
        short8 af[2], bfr[4];
        #pragma unroll
        for (int i = 0; i < 2; i++)
            af[i]  = *(const short8*)&As[(waveM*32 + i*16 + r16) * BKP + q*8];
        #pragma unroll
        for (int j = 0; j < 4; j++)
            bfr[j] = *(const short8*)&Bs[(waveN*64 + j*16 + r16) * BKP + q*8];
        #pragma unroll
        for (int i = 0; i < 2; i++)
            #pragma unroll
            for (int j = 0; j < 4; j++)
                acc[i][j] = __builtin_amdgcn_mfma_f32_16x16x32_bf16(af[i], bfr[j], acc[i][j], 0, 0, 0);
        __syncthreads();
    }

    int q = lane >> 4;
    int c16 = lane & 15;
    #pragma unroll
    for (int i = 0; i < 2; i++){
        #pragma unroll
        for (int j = 0; j < 4; j++){
            int gcol = bn + waveN*64 + j*16 + c16;
            float bvv = (MODE >= 1) ? bf2f(bias[gcol]) : 0.f;
            #pragma unroll
            for (int r = 0; r < 4; r++){
                int grow = bm + waveM*32 + i*16 + q*4 + r;
                if (grow < M){
                    float v = acc[i][j][r] + bvv;
                    if (MODE == 2) v = (v > 0.f) ? v : expm1f(v);
                    if (OUTF) ((float*)Cv)[(size_t)grow * N + gcol] = v;
                    else      ((u16*)Cv)[(size_t)grow * N + gcol] = f2bf(v);
                }
            }
        }
    }
}

// ---------------- pull aggregation (+bias+PReLU), F features ---------------
// Static blocked layout; 8-edge groups with SW-pipelined index prefetch.
// out = prelu( di*( sum_e dis[s_e]*row_e + di*row_self ) + bias )
template<int F, int NPB>
__global__ __launch_bounds__(F/8*NPB) void aggregate(
    const u16* __restrict__ XW, const int* __restrict__ rowstart,
    const int* __restrict__ csr_src, const float* __restrict__ dis,
    const u16* __restrict__ bias, const u16* __restrict__ aptr,
    u16* __restrict__ out, int N)
{
    int node = blockIdx.x * NPB + threadIdx.y;
    if (node >= N) return;
    int tf = threadIdx.x * 8;
    float a  = bf2f(aptr[0]);
    float di = dis[node];
    int e0 = rowstart[node], e1 = rowstart[node + 1];
    float acc[8] = {0,0,0,0,0,0,0,0};
    int ng = (e1 - e0) >> 3;
    int si[8]; float ci[8];
    if (ng > 0){
        #pragma unroll
        for (int u = 0; u < 8; u++) si[u] = csr_src[e0 + u];
        #pragma unroll
        for (int u = 0; u < 8; u++) ci[u] = dis[si[u]];
    }
    for (int g = 0; g < ng; g++){
        short8 vi[8];
        #pragma unroll
        for (int u = 0; u < 8; u++)
            vi[u] = *(const short8*)(XW + (size_t)si[u] * F + tf);
        int sn[8]; float cn[8];
        bool more = (g + 1) < ng;
        if (more){   // prefetch next group's indices+coeffs while rows in flight
            int base = e0 + (g + 1) * 8;
            #pragma unroll
            for (int u = 0; u < 8; u++) sn[u] = csr_src[base + u];
            #pragma unroll
            for (int u = 0; u < 8; u++) cn[u] = dis[sn[u]];
        }
        #pragma unroll
        for (int u = 0; u < 8; u++)
            #pragma unroll
            for (int j = 0; j < 8; j++)
                acc[j] += ci[u] * bf2f((u16)vi[u][j]);
        if (more){
            #pragma unroll
            for (int u = 0; u < 8; u++){ si[u] = sn[u]; ci[u] = cn[u]; }
        }
    }
    int e = e0 + ng * 8;
    for (; e + 4 <= e1; e += 4){
        int s0 = csr_src[e], s1 = csr_src[e+1], s2 = csr_src[e+2], s3 = csr_src[e+3];
        float c0 = dis[s0], c1 = dis[s1], c2 = dis[s2], c3 = dis[s3];
        short8 v0 = *(const short8*)(XW + (size_t)s0 * F + tf);
        short8 v1 = *(const short8*)(XW + (size_t)s1 * F + tf);
        short8 v2 = *(const short8*)(XW + (size_t)s2 * F + tf);
        short8 v3 = *(const short8*)(XW + (size_t)s3 * F + tf);
        #pragma unroll
        for (int j = 0; j < 8; j++)
            acc[j] += c0*bf2f((u16)v0[j]) + c1*bf2f((u16)v1[j])
                    + c2*bf2f((u16)v2[j]) + c3*bf2f((u16)v3[j]);
    }
    for (; e < e1; e++){
        int s = csr_src[e];
        float c = dis[s];
        short8 v = *(const short8*)(XW + (size_t)s * F + tf);
        #pragma unroll
        for (int j = 0; j < 8; j++) acc[j] += c * bf2f((u16)v[j]);
    }
    {   // self-loop
        short8 v = *(const short8*)(XW + (size_t)node * F + tf);
        #pragma unroll
        for (int j = 0; j < 8; j++) acc[j] += di * bf2f((u16)v[j]);
    }
    short8 bv = *(const short8*)(bias + tf);
    short8 o;
    #pragma unroll
    for (int j = 0; j < 8; j++){
        float x = di * acc[j] + bf2f((u16)bv[j]);
        x = (x > 0.f) ? x : a * x;
        o[j] = (short)f2bf(x);
    }
    *(short8*)(out + (size_t)node * F + tf) = o;
}

// ---------------- launch ----------------------------------------------------
extern "C" void kernel_launch(void* const* d_in, const int* in_sizes, int n_in,
                              void* d_out, int out_size, void* d_ws, size_t ws_size,
                              hipStream_t stream)
{
    int iX=0, iEI=1, iW1=2, ib1=3, iW2=4, ib2=5, ia=6, iW3=7, ib3=8, iW4=9, ib4=10;
    {
        int jX=-1,jEI=-1,jW1=-1,jb1=-1,jW2=-1,ja=-1,jW3=-1,jW4=-1,jb2=-1,jb3=-1,jb4=-1;
        int n64k=0, n256=0;
        for (int i = 0; i < n_in; i++){
            switch (in_sizes[i]){
                case 10240000: jX = i; break;
                case 640000:   jEI = i; break;
                case 262144:   jW1 = i; break;
                case 131072:   jW2 = i; break;
                case 512:      jb1 = i; break;
                case 1:        ja = i; break;
                case 65536:    if (n64k++ == 0) jW3 = i; else jW4 = i; break;
                case 256: {
                    int k = n256++;
                    if (k == 0) jb2 = i; else if (k == 1) jb3 = i; else jb4 = i;
                } break;
                default: break;
            }
        }
        if (jX>=0&&jEI>=0&&jW1>=0&&jb1>=0&&jW2>=0&&ja>=0&&jW3>=0&&jW4>=0&&jb2>=0&&jb3>=0&&jb4>=0){
            iX=jX; iEI=jEI; iW1=jW1; ib1=jb1; iW2=jW2; ib2=jb2; ia=ja; iW3=jW3; ib3=jb3; iW4=jW4; ib4=jb4;
        }
    }
    int N = in_sizes[iX] / 512;
    int E = in_sizes[iEI] / 2;
    const int* EI = (const int*)d_in[iEI];
    float* OUT = (float*)d_out;                 // fp32 output (N*256*4 bytes)
    u16*   S   = (u16*)d_out;                   // same bytes as bf16 N x 512 scratch

    char* ws = (char*)d_ws;
    size_t off = 0;
    auto alloc = [&](size_t bytes)->char*{
        char* p = ws + off;
        off = (off + bytes + 255) & ~(size_t)255;
        return p;
    };
    int nb = (N + 255) / 256;                   // scan blocks (N<=32768)
    int*   cnt  = (int*)  alloc((size_t)N*4);
    int*   incl = (int*)  alloc((size_t)N*4);
    int*   bsum = (int*)  alloc(512);
    int*   efmt = (int*)  alloc(4);
    int*   f32f = (int*)  alloc(4);
    int*   zf   = (int*)  alloc(4);
    float* dis  = (float*)alloc((size_t)N*4);
    int*   rs   = (int*)  alloc((size_t)(N+1)*4);
    int*   cur  = (int*)  alloc((size_t)N*4);
    int*   csr  = (int*)  alloc((size_t)E*4);
    u16*   WT1  = (u16*)  alloc((size_t)512*512*2);
    u16*   WT2  = (u16*)  alloc((size_t)256*512*2);
    u16*   WT3  = (u16*)  alloc((size_t)256*256*2);
    u16*   WT4  = (u16*)  alloc((size_t)256*256*2);
    u16*   b1c  = (u16*)  alloc((size_t)512*2);
    u16*   b2c  = (u16*)  alloc((size_t)256*2);
    u16*   b3c  = (u16*)  alloc((size_t)256*2);
    u16*   b4c  = (u16*)  alloc((size_t)256*2);
    u16*   ac   = (u16*)  alloc((size_t)8*2);
    u16*   h1   = (u16*)  alloc((size_t)N*512*2);   // 20.48 MB
    u16*   P    = (u16*)  alloc((size_t)N*256*2);   // 10.24 MB

    if (ws_size < off) return;

    probe_all<<<1, 256, 0, stream>>>((const u16*)d_in[iW1], EI,
                                     d_in[ib1], d_in[ib2], d_in[ib3], d_in[ib4],
                                     d_in[ia], f32f, efmt, zf, cnt, N,
                                     b1c, b2c, b3c, b4c, ac);

    int egrid = (E + 255) / 256;
    deg_count<<<egrid, 256, 0, stream>>>(EI, efmt, cnt, E, N);
    scan1<<<nb, 256, 0, stream>>>(cnt, incl, bsum, N);
    scan23<<<nb, 256, 0, stream>>>(cnt, incl, bsum, nb, rs, cur, dis, N);
    csr_fill<<<egrid, 256, 0, stream>>>(EI, efmt, cur, csr, E, N);

    transpose_all<<<dim3(16, 16, 4), dim3(32, 8), 0, stream>>>(
        d_in[iW1], d_in[iW2], d_in[iW3], d_in[iW4], f32f, WT1, WT2, WT3, WT4);

    int gm = (N + TM - 1) / TM;           // 313
    dim3 g512(gm, 512 / TN);              // 1252 blocks
    dim3 g256(gm, 256 / TN);              //  626 blocks

    // layer 1: full-width XW1 -> S (bf16 scratch in OUT buffer)
    gemm_mfma<0,0><<<g512, 256, 0, stream>>>(d_in[iX], f32f, WT1, nullptr, S, N, 512, 512);
    aggregate<512,2><<<(N+1)/2, dim3(64,2), 0, stream>>>(S, rs, csr, dis, b1c, ac, h1, N);

    // layer 2: h1 @ W2 -> P ; aggregate -> Q (OUT bytes as bf16; S dead)
    u16* Q = (u16*)d_out;
    gemm_mfma<0,0><<<g256, 256, 0, stream>>>(h1, zf, WT2, nullptr, P, N, 512, 256);
    aggregate<256,4><<<(N+3)/4, dim3(32,4), 0, stream>>>(P, rs, csr, dis, b2c, ac, Q, N);

    // projection MLP: ELU(Q @ W3 + b3) -> P ; P @ W4 + b4 -> OUT (fp32)
    gemm_mfma<2,0><<<g256, 256, 0, stream>>>(Q, zf, WT3, b3c, P, N, 256, 256);
    gemm_mfma<1,1><<<g256, 256, 0, stream>>>(P, zf, WT4, b4c, OUT, N, 256, 256);
}